// Round 3
// baseline (788.171 us; speedup 1.0000x reference)
//
#include <hip/hip_runtime.h>
#include <float.h>
#include <stdint.h>

#define EPSF 1e-6f

constexpr int Dc = 512, Kc = 4096, DOc = 1024;
constexpr int Mc = 16384;                 // 4*4096 rows
constexpr int NHALF = 2048;               // centers per half-pass

typedef _Float16 f16x8 __attribute__((ext_vector_type(8)));
typedef float f32x4 __attribute__((ext_vector_type(4)));
typedef __attribute__((address_space(1))) unsigned int gu32;
typedef __attribute__((address_space(3))) unsigned int lu32;

struct BestRec { double d; int idx; int pad; };

// ---------- convert kernels ----------
__global__ __launch_bounds__(256) void cvt_x_kernel(const float* __restrict__ x,
                                                    _Float16* __restrict__ xh) {
  const size_t base = ((size_t)blockIdx.x * 256 + threadIdx.x) * 8;
  float4 v0 = *(const float4*)(x + base);
  float4 v1 = *(const float4*)(x + base + 4);
  float v[8] = {v0.x, v0.y, v0.z, v0.w, v1.x, v1.y, v1.z, v1.w};
  f16x8 h;
#pragma unroll
  for (int i = 0; i < 8; ++i) h[i] = (_Float16)(v[i] + EPSF);
  *(f16x8*)(xh + base) = h;
}

__global__ __launch_bounds__(256) void cvt_c_kernel(const float* __restrict__ centers,
                                                    _Float16* __restrict__ ch,
                                                    float* __restrict__ c2) {
  const int lane = threadIdx.x & 63, w = threadIdx.x >> 6;
  const int row = blockIdx.x * 4 + w;
  const size_t base = (size_t)row * Dc + lane * 8;
  float4 v0 = *(const float4*)(centers + base);
  float4 v1 = *(const float4*)(centers + base + 4);
  float v[8] = {v0.x, v0.y, v0.z, v0.w, v1.x, v1.y, v1.z, v1.w};
  f16x8 h;
  float s = 0.f;
#pragma unroll
  for (int i = 0; i < 8; ++i) { s += v[i] * v[i]; h[i] = (_Float16)v[i]; }
  *(f16x8*)(ch + base) = h;
#pragma unroll
  for (int off = 32; off > 0; off >>= 1) s += __shfl_down(s, off, 64);
  if (lane == 0) c2[row] = s;
}

__global__ __launch_bounds__(256) void cvt_w_kernel(const float* __restrict__ W,
                                                    _Float16* __restrict__ whT) {
  const int g = blockIdx.x * 256 + threadIdx.x;
  const int n = g & (DOc - 1), d8 = g >> 10;
  f16x8 h;
#pragma unroll
  for (int r = 0; r < 8; ++r) h[r] = (_Float16)W[(size_t)(d8 * 8 + r) * DOc + n];
  *(f16x8*)(whT + (size_t)n * Dc + d8 * 8) = h;
}

// ---------- distance GEMM (hh only, m97 shape) + u16 quantized store ----------
__global__ __launch_bounds__(256, 2) void dist_hh_kernel(
    const _Float16* __restrict__ xh, const _Float16* __restrict__ chh,
    const float* __restrict__ c2h, unsigned short* __restrict__ dq) {
  constexpr int BM = 128, BN = 128, BK = 32;
  __shared__ __align__(16) _Float16 smem[2 * BM * BK];  // 16 KB; sA | sB; reused as u16 tile
  _Float16* sA = smem;
  _Float16* sB = smem + BM * BK;
  unsigned short* t = (unsigned short*)smem;            // [64][128] u16

  const int tid = threadIdx.x;
  const int lane = tid & 63, w = tid >> 6;
  const int n0 = blockIdx.x * BN;       // within-half center offset
  const int row0 = blockIdx.y * BM;
  const int srow = w * 16 + (lane >> 2);
  const int scol = (lane & 3) * 8;
  const int fr = lane & 15, kq = lane >> 4;
  const int m0 = w * 32;

  f32x4 acc[2][8];
#pragma unroll
  for (int i = 0; i < 2; ++i)
#pragma unroll
    for (int j = 0; j < 8; ++j) acc[i][j] = (f32x4){0.f, 0.f, 0.f, 0.f};

  for (int d0 = 0; d0 < Dc; d0 += BK) {
#pragma unroll
    for (int r = 0; r < 2; ++r) {
      const int rr = r * 64 + srow;
      const size_t gA = (size_t)(row0 + rr) * Dc + d0 + scol;
      const size_t gB = (size_t)(n0 + rr) * Dc + d0 + scol;
      const int lo = rr * BK + scol;
      __builtin_amdgcn_global_load_lds((const gu32*)(xh + gA), (lu32*)(sA + lo), 16, 0, 0);
      __builtin_amdgcn_global_load_lds((const gu32*)(chh + gB), (lu32*)(sB + lo), 16, 0, 0);
    }
    __syncthreads();

    f16x8 a[2], b[8];
#pragma unroll
    for (int i = 0; i < 2; ++i)
      a[i] = *(const f16x8*)&sA[(m0 + 16 * i + fr) * BK + kq * 8];
#pragma unroll
    for (int j = 0; j < 8; ++j)
      b[j] = *(const f16x8*)&sB[(16 * j + fr) * BK + kq * 8];
#pragma unroll
    for (int i = 0; i < 2; ++i)
#pragma unroll
      for (int j = 0; j < 8; ++j)
        acc[i][j] = __builtin_amdgcn_mfma_f32_16x16x32_f16(a[i], b[j], acc[i][j], 0, 0, 0);
    __syncthreads();
  }

  // epilogue: d~ = c2[n] - 2*dot, quantize u16 (step 1/32, offset 256),
  // LDS transpose to coalesced row-major stores. Clamp-low is SAFE: clamped
  // values become candidates and get fp64-refined.
  float c2v[8];
#pragma unroll
  for (int j = 0; j < 8; ++j) c2v[j] = c2h[n0 + 16 * j + fr];

#pragma unroll
  for (int i = 0; i < 2; ++i) {
    __syncthreads();
#pragma unroll
    for (int reg = 0; reg < 4; ++reg) {
      const int lrow = w * 16 + kq * 4 + reg;  // 0..63
#pragma unroll
      for (int j = 0; j < 8; ++j) {
        const float d = c2v[j] - 2.0f * acc[i][j][reg];
        int u = __float2int_rn((d + 256.0f) * 32.0f);
        u = min(65535, max(0, u));
        t[lrow * 128 + 16 * j + fr] = (unsigned short)u;
      }
    }
    __syncthreads();
#pragma unroll
    for (int cc = 0; cc < 4; ++cc) {
      const int chk = tid + 256 * cc;        // 0..1023 16B-chunks
      const int lr = chk >> 4, c8 = chk & 15;
      const int grow = row0 + (lr >> 4) * 32 + 16 * i + (lr & 15);
      uint4 v = *(const uint4*)&t[lr * 128 + c8 * 8];
      *(uint4*)&dq[(size_t)grow * NHALF + n0 + c8 * 8] = v;
    }
  }
}

// ---------- scan + fp64 refine (deterministic window) ----------
__global__ __launch_bounds__(256) void scan_refine_kernel(
    const unsigned short* __restrict__ dq, const float* __restrict__ x,
    const float* __restrict__ centers, int halfbase, int mode,
    BestRec* __restrict__ best, int* __restrict__ sel) {
  const int w = threadIdx.x >> 6, l = threadIdx.x & 63;
  const int row = blockIdx.x * 4 + w;
  const unsigned short* dr = dq + (size_t)row * NHALF;

  uint4 v[4];
#pragma unroll
  for (int k = 0; k < 4; ++k) v[k] = *(const uint4*)&dr[k * 512 + l * 8];

  // per-lane u16 min, then wave min
  unsigned mn = 0xFFFFu;
#pragma unroll
  for (int k = 0; k < 4; ++k) {
    const unsigned* u = (const unsigned*)&v[k];
#pragma unroll
    for (int q = 0; q < 4; ++q) {
      mn = min(mn, u[q] & 0xFFFFu);
      mn = min(mn, u[q] >> 16);
    }
  }
#pragma unroll
  for (int m = 1; m < 64; m <<= 1) mn = min(mn, (unsigned)__shfl_xor((int)mn, m, 64));

  // row norm for the deterministic error window
  const float* xr = x + (size_t)row * Dc;
  float4 a0 = *(const float4*)(xr + l * 8);
  float4 a1 = *(const float4*)(xr + l * 8 + 4);
  float av[8] = {a0.x, a0.y, a0.z, a0.w, a1.x, a1.y, a1.z, a1.w};
  float x2 = 0.f;
#pragma unroll
  for (int i = 0; i < 8; ++i) { const float q = av[i] + EPSF; x2 += q * q; }
#pragma unroll
  for (int m = 1; m < 64; m <<= 1) x2 += __shfl_xor(x2, m, 64);
  // window (quant units): 64 * [2(2e+e^2)*||c||max*||x|| + slack], e=2^-11, ||c||<=sqrt(512)
  const unsigned thr = mn + (unsigned)(2.829f * sqrtf(x2) + 8.0f);

  // refine every candidate <= thr in fp64 (matches np selection; verified R1/R2)
  double bd = DBL_MAX;
  int bi = 0x7FFFFFFF;
#pragma unroll
  for (int k = 0; k < 4; ++k) {
    const unsigned* u = (const unsigned*)&v[k];
#pragma unroll
    for (int q = 0; q < 4; ++q) {
#pragma unroll
      for (int h = 0; h < 2; ++h) {
        const unsigned uv = h ? (u[q] >> 16) : (u[q] & 0xFFFFu);
        if (uv <= thr) {
          const int g = halfbase + k * 512 + l * 8 + q * 2 + h;
          const float* cr = centers + (size_t)g * Dc;
          double dot = 0.0, cc2 = 0.0;
          for (int d = 0; d < Dc; ++d) {
            const float xq = xr[d] + EPSF;
            const double cd = (double)cr[d];
            dot += (double)xq * cd;
            cc2 += cd * cd;
          }
          const double dd = cc2 - 2.0 * dot;
          if (dd < bd || (dd == bd && g < bi)) { bd = dd; bi = g; }
        }
      }
    }
  }
#pragma unroll
  for (int m = 1; m < 64; m <<= 1) {
    const double od = __longlong_as_double(__shfl_xor(__double_as_longlong(bd), m, 64));
    const int oi = __shfl_xor(bi, m, 64);
    if (od < bd || (od == bd && oi < bi)) { bd = od; bi = oi; }
  }
  if (l == 0) {
    if (mode == 0) {
      BestRec r; r.d = bd; r.idx = bi; r.pad = 0;
      best[row] = r;
    } else {
      const BestRec p = best[row];
      if (p.d < bd || (p.d == bd && p.idx < bi)) { bd = p.d; bi = p.idx; }
      sel[row] = bi;
    }
  }
}

// ---------- projection: out = centers[sel] @ W + b  (f16 MFMA) ----------
__global__ __launch_bounds__(256, 2) void proj_mfma_kernel(
    const _Float16* __restrict__ ch, const int* __restrict__ sel,
    const _Float16* __restrict__ whT, const float* __restrict__ bias,
    float* __restrict__ out) {
  constexpr int BM = 128, BN = 128, BK = 32;
  __shared__ __align__(16) _Float16 sA[BM * BK], sB[BN * BK];
  __shared__ int ssel[BM];

  const int tid = threadIdx.x;
  const int lane = tid & 63, w = tid >> 6;
  const int row0 = blockIdx.x * BM;
  const int n0 = blockIdx.y * BN;
  const int srow = w * 16 + (lane >> 2);
  const int scol = (lane & 3) * 8;
  const int fr = lane & 15, kq = lane >> 4;
  const int m0 = w * 32;

  if (tid < BM) ssel[tid] = sel[row0 + tid];
  __syncthreads();

  f32x4 acc[2][8];
#pragma unroll
  for (int i = 0; i < 2; ++i)
#pragma unroll
    for (int j = 0; j < 8; ++j) acc[i][j] = (f32x4){0.f, 0.f, 0.f, 0.f};

  for (int d0 = 0; d0 < Dc; d0 += BK) {
#pragma unroll
    for (int r = 0; r < 2; ++r) {
      const int rr = r * 64 + srow;
      const size_t gA = (size_t)ssel[rr] * Dc + d0 + scol;
      const size_t gB = (size_t)(n0 + rr) * Dc + d0 + scol;
      const int lo = rr * BK + scol;
      __builtin_amdgcn_global_load_lds((const gu32*)(ch + gA), (lu32*)(sA + lo), 16, 0, 0);
      __builtin_amdgcn_global_load_lds((const gu32*)(whT + gB), (lu32*)(sB + lo), 16, 0, 0);
    }
    __syncthreads();

    f16x8 a[2], b[8];
#pragma unroll
    for (int i = 0; i < 2; ++i)
      a[i] = *(const f16x8*)&sA[(m0 + 16 * i + fr) * BK + kq * 8];
#pragma unroll
    for (int j = 0; j < 8; ++j)
      b[j] = *(const f16x8*)&sB[(16 * j + fr) * BK + kq * 8];
#pragma unroll
    for (int i = 0; i < 2; ++i)
#pragma unroll
      for (int j = 0; j < 8; ++j)
        acc[i][j] = __builtin_amdgcn_mfma_f32_16x16x32_f16(a[i], b[j], acc[i][j], 0, 0, 0);
    __syncthreads();
  }

#pragma unroll
  for (int j = 0; j < 8; ++j) {
    const int col = n0 + 16 * j + fr;
    const float bb = bias[col];
#pragma unroll
    for (int i = 0; i < 2; ++i)
#pragma unroll
      for (int reg = 0; reg < 4; ++reg)
        out[(size_t)(row0 + m0 + 16 * i + 4 * kq + reg) * DOc + col] =
            acc[i][j][reg] + bb;
  }
}

extern "C" void kernel_launch(void* const* d_in, const int* in_sizes, int n_in,
                              void* d_out, int out_size, void* d_ws, size_t ws_size,
                              hipStream_t stream) {
  const float* x = (const float*)d_in[0];        // [4,4096,512]
  const float* centers = (const float*)d_in[1];  // [4096,512]
  const float* W = (const float*)d_in[2];        // [512,1024]
  const float* b = (const float*)d_in[3];        // [1024]
  float* out = (float*)d_out;                    // [4,4096,1024] fp32

  // dq (u16 [16384][2048] = 67.1 MB) lives in d_out; proj overwrites it last.
  unsigned short* dq = (unsigned short*)d_out;

  // workspace (~22.4 MB)
  char* ws = (char*)d_ws;
  _Float16* xh = (_Float16*)(ws);                 // 16.78 MB
  _Float16* ch = (_Float16*)(ws + 16777216);      // 4.19 MB
  _Float16* whT = (_Float16*)(ws + 20971520);     // 1.05 MB
  float* c2 = (float*)(ws + 22020096);            // 16 KB
  BestRec* best = (BestRec*)(ws + 22036480);      // 256 KB
  int* sel = (int*)(ws + 22298624);               // 64 KB

  cvt_x_kernel<<<Mc * Dc / (256 * 8), 256, 0, stream>>>(x, xh);
  cvt_c_kernel<<<Kc / 4, 256, 0, stream>>>(centers, ch, c2);
  cvt_w_kernel<<<Dc * DOc / (256 * 8), 256, 0, stream>>>(W, whT);

  for (int half = 0; half < 2; ++half) {
    const int hb = half * NHALF;
    dist_hh_kernel<<<dim3(NHALF / 128, Mc / 128), 256, 0, stream>>>(
        xh, ch + (size_t)hb * Dc, c2 + hb, dq);
    scan_refine_kernel<<<Mc / 4, 256, 0, stream>>>(dq, x, centers, hb, half,
                                                   best, sel);
  }
  proj_mfma_kernel<<<dim3(Mc / 128, DOc / 128), 256, 0, stream>>>(ch, sel, whT, b, out);
}

// Round 4
// 670.184 us; speedup vs baseline: 1.1761x; 1.1761x over previous
//
#include <hip/hip_runtime.h>
#include <float.h>
#include <stdint.h>

#define EPSF 1e-6f

constexpr int Dc = 512, Kc = 4096, DOc = 1024;
constexpr int Mc = 16384;                 // 4*4096 rows
constexpr int NHALF = 2048;               // centers per half-pass
constexpr unsigned CAND_CAP = 4u << 20;   // 4M candidate slots (16 MB)

typedef _Float16 f16x8 __attribute__((ext_vector_type(8)));
typedef float f32x4 __attribute__((ext_vector_type(4)));
typedef __attribute__((address_space(1))) unsigned int gu32;
typedef __attribute__((address_space(3))) unsigned int lu32;
typedef unsigned long long u64;

// ---------- init: best=~0, count=0 (ws is poisoned 0xAA each call) ----------
__global__ __launch_bounds__(256) void init_kernel(u64* __restrict__ best,
                                                   unsigned* __restrict__ count) {
  const int i = blockIdx.x * 256 + threadIdx.x;
  best[i] = ~0ULL;
  if (i == 0) *count = 0;
}

// ---------- convert x: f16 cast + per-row candidate window ----------
__global__ __launch_bounds__(256) void cvt_x_kernel(const float* __restrict__ x,
                                                    _Float16* __restrict__ xh,
                                                    unsigned* __restrict__ wthr) {
  const int lane = threadIdx.x & 63, w = threadIdx.x >> 6;
  const int row = blockIdx.x * 4 + w;
  const size_t base = (size_t)row * Dc + lane * 8;
  float4 v0 = *(const float4*)(x + base);
  float4 v1 = *(const float4*)(x + base + 4);
  float v[8] = {v0.x, v0.y, v0.z, v0.w, v1.x, v1.y, v1.z, v1.w};
  f16x8 h;
  float s = 0.f;
#pragma unroll
  for (int i = 0; i < 8; ++i) {
    const float q = v[i] + EPSF;
    h[i] = (_Float16)q;
    s += q * q;
  }
  *(f16x8*)(xh + base) = h;
#pragma unroll
  for (int m = 1; m < 64; m <<= 1) s += __shfl_xor(s, m, 64);
  // window (u16 quant units): 64*[2(2e+e^2)*||c||max*||x||] + slack; e=2^-11
  if (lane == 0) wthr[row] = (unsigned)(2.829f * sqrtf(s) + 8.0f);
}

__global__ __launch_bounds__(256) void cvt_c_kernel(const float* __restrict__ centers,
                                                    _Float16* __restrict__ ch,
                                                    float* __restrict__ c2) {
  const int lane = threadIdx.x & 63, w = threadIdx.x >> 6;
  const int row = blockIdx.x * 4 + w;
  const size_t base = (size_t)row * Dc + lane * 8;
  float4 v0 = *(const float4*)(centers + base);
  float4 v1 = *(const float4*)(centers + base + 4);
  float v[8] = {v0.x, v0.y, v0.z, v0.w, v1.x, v1.y, v1.z, v1.w};
  f16x8 h;
  float s = 0.f;
#pragma unroll
  for (int i = 0; i < 8; ++i) { s += v[i] * v[i]; h[i] = (_Float16)v[i]; }
  *(f16x8*)(ch + base) = h;
#pragma unroll
  for (int off = 32; off > 0; off >>= 1) s += __shfl_down(s, off, 64);
  if (lane == 0) c2[row] = s;
}

__global__ __launch_bounds__(256) void cvt_w_kernel(const float* __restrict__ W,
                                                    _Float16* __restrict__ whT) {
  const int g = blockIdx.x * 256 + threadIdx.x;
  const int n = g & (DOc - 1), d8 = g >> 10;
  f16x8 h;
#pragma unroll
  for (int r = 0; r < 8; ++r) h[r] = (_Float16)W[(size_t)(d8 * 8 + r) * DOc + n];
  *(f16x8*)(whT + (size_t)n * Dc + d8 * 8) = h;
}

// ---------- distance GEMM (hh only, m97 shape) + u16 quantized store ----------
__global__ __launch_bounds__(256, 2) void dist_hh_kernel(
    const _Float16* __restrict__ xh, const _Float16* __restrict__ chh,
    const float* __restrict__ c2h, unsigned short* __restrict__ dq) {
  constexpr int BM = 128, BN = 128, BK = 32;
  __shared__ __align__(16) _Float16 smem[2 * BM * BK];  // sA | sB; reused as u16 tile
  _Float16* sA = smem;
  _Float16* sB = smem + BM * BK;
  unsigned short* t = (unsigned short*)smem;            // [64][128] u16

  const int tid = threadIdx.x;
  const int lane = tid & 63, w = tid >> 6;
  const int n0 = blockIdx.x * BN;
  const int row0 = blockIdx.y * BM;
  const int srow = w * 16 + (lane >> 2);
  const int scol = (lane & 3) * 8;
  const int fr = lane & 15, kq = lane >> 4;
  const int m0 = w * 32;

  f32x4 acc[2][8];
#pragma unroll
  for (int i = 0; i < 2; ++i)
#pragma unroll
    for (int j = 0; j < 8; ++j) acc[i][j] = (f32x4){0.f, 0.f, 0.f, 0.f};

  for (int d0 = 0; d0 < Dc; d0 += BK) {
#pragma unroll
    for (int r = 0; r < 2; ++r) {
      const int rr = r * 64 + srow;
      const size_t gA = (size_t)(row0 + rr) * Dc + d0 + scol;
      const size_t gB = (size_t)(n0 + rr) * Dc + d0 + scol;
      const int lo = rr * BK + scol;
      __builtin_amdgcn_global_load_lds((const gu32*)(xh + gA), (lu32*)(sA + lo), 16, 0, 0);
      __builtin_amdgcn_global_load_lds((const gu32*)(chh + gB), (lu32*)(sB + lo), 16, 0, 0);
    }
    __syncthreads();

    f16x8 a[2], b[8];
#pragma unroll
    for (int i = 0; i < 2; ++i)
      a[i] = *(const f16x8*)&sA[(m0 + 16 * i + fr) * BK + kq * 8];
#pragma unroll
    for (int j = 0; j < 8; ++j)
      b[j] = *(const f16x8*)&sB[(16 * j + fr) * BK + kq * 8];
#pragma unroll
    for (int i = 0; i < 2; ++i)
#pragma unroll
      for (int j = 0; j < 8; ++j)
        acc[i][j] = __builtin_amdgcn_mfma_f32_16x16x32_f16(a[i], b[j], acc[i][j], 0, 0, 0);
    __syncthreads();
  }

  // epilogue: d~ = c2[n] - 2*dot, quantize u16 (step 1/32, offset 256),
  // LDS transpose to coalesced stores. Clamp-low is SAFE (clamped -> refined).
  float c2v[8];
#pragma unroll
  for (int j = 0; j < 8; ++j) c2v[j] = c2h[n0 + 16 * j + fr];

#pragma unroll
  for (int i = 0; i < 2; ++i) {
    __syncthreads();
#pragma unroll
    for (int reg = 0; reg < 4; ++reg) {
      const int lrow = w * 16 + kq * 4 + reg;
#pragma unroll
      for (int j = 0; j < 8; ++j) {
        const float d = c2v[j] - 2.0f * acc[i][j][reg];
        int u = __float2int_rn((d + 256.0f) * 32.0f);
        u = min(65535, max(0, u));
        t[lrow * 128 + 16 * j + fr] = (unsigned short)u;
      }
    }
    __syncthreads();
#pragma unroll
    for (int cc = 0; cc < 4; ++cc) {
      const int chk = tid + 256 * cc;
      const int lr = chk >> 4, c8 = chk & 15;
      const int grow = row0 + (lr >> 4) * 32 + 16 * i + (lr & 15);
      uint4 v = *(const uint4*)&t[lr * 128 + c8 * 8];
      *(uint4*)&dq[(size_t)grow * NHALF + n0 + c8 * 8] = v;
    }
  }
}

// ---------- scan: row min + compacted candidate emit ----------
__global__ __launch_bounds__(256) void scan_kernel(
    const unsigned short* __restrict__ dq, const unsigned* __restrict__ wthr,
    int halfbase, unsigned* __restrict__ cand, unsigned* __restrict__ count) {
  const int w = threadIdx.x >> 6, l = threadIdx.x & 63;
  const int row = blockIdx.x * 4 + w;
  const unsigned short* dr = dq + (size_t)row * NHALF;

  uint4 v[4];
#pragma unroll
  for (int k = 0; k < 4; ++k) v[k] = *(const uint4*)&dr[k * 512 + l * 8];

  unsigned mn = 0xFFFFu;
#pragma unroll
  for (int k = 0; k < 4; ++k) {
    const unsigned* u = (const unsigned*)&v[k];
#pragma unroll
    for (int q = 0; q < 4; ++q) {
      mn = min(mn, u[q] & 0xFFFFu);
      mn = min(mn, u[q] >> 16);
    }
  }
#pragma unroll
  for (int m = 1; m < 64; m <<= 1) mn = min(mn, (unsigned)__shfl_xor((int)mn, m, 64));
  const unsigned thr = mn + wthr[row];

  // count per-lane candidates
  unsigned cnt = 0;
#pragma unroll
  for (int k = 0; k < 4; ++k) {
    const unsigned* u = (const unsigned*)&v[k];
#pragma unroll
    for (int q = 0; q < 4; ++q) {
      cnt += ((u[q] & 0xFFFFu) <= thr);
      cnt += ((u[q] >> 16) <= thr);
    }
  }
  // wave exclusive prefix + single atomic
  unsigned inc = cnt;
#pragma unroll
  for (int m = 1; m < 64; m <<= 1) {
    const unsigned o = __shfl_up(inc, m, 64);
    if (l >= m) inc += o;
  }
  const unsigned total = __shfl(inc, 63, 64);
  unsigned base = 0;
  if (l == 63 && total) base = atomicAdd(count, total);
  base = __shfl(base, 63, 64);
  unsigned pos = base + inc - cnt;
#pragma unroll
  for (int k = 0; k < 4; ++k) {
    const unsigned* u = (const unsigned*)&v[k];
#pragma unroll
    for (int q = 0; q < 4; ++q) {
#pragma unroll
      for (int h = 0; h < 2; ++h) {
        const unsigned uv = h ? (u[q] >> 16) : (u[q] & 0xFFFFu);
        if (uv <= thr) {
          if (pos < CAND_CAP)
            cand[pos] = ((unsigned)row << 12) |
                        (unsigned)(halfbase + k * 512 + l * 8 + q * 2 + h);
          ++pos;
        }
      }
    }
  }
}

// ---------- refine: one wave per candidate, fp64-exact, atomicMin key ----------
__global__ __launch_bounds__(256) void refine_kernel(
    const unsigned* __restrict__ cand, const unsigned* __restrict__ count,
    const float* __restrict__ x, const float* __restrict__ centers,
    u64* __restrict__ best) {
  const int l = threadIdx.x & 63;
  const int wid = (int)((blockIdx.x * 256 + threadIdx.x) >> 6);
  const int nw = gridDim.x * 4;
  const unsigned n = min(*count, CAND_CAP);

  for (unsigned c = wid; c < n; c += nw) {
    const unsigned pk = cand[c];
    const int row = (int)(pk >> 12), g = (int)(pk & 0xFFFu);
    const float* xr = x + (size_t)row * Dc + l * 8;
    const float* cr = centers + (size_t)g * Dc + l * 8;
    float4 a0 = *(const float4*)xr, a1 = *(const float4*)(xr + 4);
    float4 b0 = *(const float4*)cr, b1 = *(const float4*)(cr + 4);
    const float xa[8] = {a0.x, a0.y, a0.z, a0.w, a1.x, a1.y, a1.z, a1.w};
    const float ca[8] = {b0.x, b0.y, b0.z, b0.w, b1.x, b1.y, b1.z, b1.w};
    double s = 0.0;
#pragma unroll
    for (int i = 0; i < 8; ++i) {
      const double cd = (double)ca[i];
      const double xq = (double)(xa[i] + EPSF);  // fp32 x+eps, matching reference
      s += cd * cd - 2.0 * xq * cd;
    }
#pragma unroll
    for (int m = 1; m < 64; m <<= 1) s += __shfl_xor(s, m, 64);
    if (l == 0) {
      // sortable key: d2' shifted positive (x2<=~700 << 16384), low 12 bits = idx
      const u64 key = ((u64)__double_as_longlong(s + 16384.0) & ~0xFFFULL) | (unsigned)g;
      atomicMin(&best[row], key);
    }
  }
}

// ---------- projection: out = centers[best] @ W + b  (f16 MFMA) ----------
__global__ __launch_bounds__(256, 2) void proj_mfma_kernel(
    const _Float16* __restrict__ ch, const u64* __restrict__ best,
    const _Float16* __restrict__ whT, const float* __restrict__ bias,
    float* __restrict__ out) {
  constexpr int BM = 128, BN = 128, BK = 32;
  __shared__ __align__(16) _Float16 sA[BM * BK], sB[BN * BK];
  __shared__ int ssel[BM];

  const int tid = threadIdx.x;
  const int lane = tid & 63, w = tid >> 6;
  const int row0 = blockIdx.x * BM;
  const int n0 = blockIdx.y * BN;
  const int srow = w * 16 + (lane >> 2);
  const int scol = (lane & 3) * 8;
  const int fr = lane & 15, kq = lane >> 4;
  const int m0 = w * 32;

  if (tid < BM) ssel[tid] = (int)(best[row0 + tid] & 0xFFFULL);
  __syncthreads();

  f32x4 acc[2][8];
#pragma unroll
  for (int i = 0; i < 2; ++i)
#pragma unroll
    for (int j = 0; j < 8; ++j) acc[i][j] = (f32x4){0.f, 0.f, 0.f, 0.f};

  for (int d0 = 0; d0 < Dc; d0 += BK) {
#pragma unroll
    for (int r = 0; r < 2; ++r) {
      const int rr = r * 64 + srow;
      const size_t gA = (size_t)ssel[rr] * Dc + d0 + scol;
      const size_t gB = (size_t)(n0 + rr) * Dc + d0 + scol;
      const int lo = rr * BK + scol;
      __builtin_amdgcn_global_load_lds((const gu32*)(ch + gA), (lu32*)(sA + lo), 16, 0, 0);
      __builtin_amdgcn_global_load_lds((const gu32*)(whT + gB), (lu32*)(sB + lo), 16, 0, 0);
    }
    __syncthreads();

    f16x8 a[2], b[8];
#pragma unroll
    for (int i = 0; i < 2; ++i)
      a[i] = *(const f16x8*)&sA[(m0 + 16 * i + fr) * BK + kq * 8];
#pragma unroll
    for (int j = 0; j < 8; ++j)
      b[j] = *(const f16x8*)&sB[(16 * j + fr) * BK + kq * 8];
#pragma unroll
    for (int i = 0; i < 2; ++i)
#pragma unroll
      for (int j = 0; j < 8; ++j)
        acc[i][j] = __builtin_amdgcn_mfma_f32_16x16x32_f16(a[i], b[j], acc[i][j], 0, 0, 0);
    __syncthreads();
  }

#pragma unroll
  for (int j = 0; j < 8; ++j) {
    const int col = n0 + 16 * j + fr;
    const float bb = bias[col];
#pragma unroll
    for (int i = 0; i < 2; ++i)
#pragma unroll
      for (int reg = 0; reg < 4; ++reg)
        out[(size_t)(row0 + m0 + 16 * i + 4 * kq + reg) * DOc + col] =
            acc[i][j][reg] + bb;
  }
}

extern "C" void kernel_launch(void* const* d_in, const int* in_sizes, int n_in,
                              void* d_out, int out_size, void* d_ws, size_t ws_size,
                              hipStream_t stream) {
  const float* x = (const float*)d_in[0];        // [4,4096,512]
  const float* centers = (const float*)d_in[1];  // [4096,512]
  const float* W = (const float*)d_in[2];        // [512,1024]
  const float* b = (const float*)d_in[3];        // [1024]
  float* out = (float*)d_out;                    // [4,4096,1024] fp32

  // dq (u16 [16384][2048] = 67.1 MB) lives in d_out; proj overwrites it last.
  unsigned short* dq = (unsigned short*)d_out;

  // workspace (~39 MB)
  char* ws = (char*)d_ws;
  _Float16* xh = (_Float16*)(ws);                 // 16.78 MB
  _Float16* ch = (_Float16*)(ws + 16777216);      // 4.19 MB
  _Float16* whT = (_Float16*)(ws + 20971520);     // 1.05 MB
  float* c2 = (float*)(ws + 22020096);            // 16 KB
  unsigned* wthr = (unsigned*)(ws + 22036480);    // 64 KB
  u64* best = (u64*)(ws + 22102016);              // 128 KB
  unsigned* count = (unsigned*)(ws + 22233088);   // 4 KB slot
  unsigned* cand = (unsigned*)(ws + 22237184);    // 16 MB

  init_kernel<<<Mc / 256, 256, 0, stream>>>(best, count);
  cvt_x_kernel<<<Mc / 4, 256, 0, stream>>>(x, xh, wthr);
  cvt_c_kernel<<<Kc / 4, 256, 0, stream>>>(centers, ch, c2);
  cvt_w_kernel<<<Dc * DOc / (256 * 8), 256, 0, stream>>>(W, whT);

  for (int half = 0; half < 2; ++half) {
    const int hb = half * NHALF;
    dist_hh_kernel<<<dim3(NHALF / 128, Mc / 128), 256, 0, stream>>>(
        xh, ch + (size_t)hb * Dc, c2 + hb, dq);
    scan_kernel<<<Mc / 4, 256, 0, stream>>>(dq, wthr, hb, cand, count);
  }
  refine_kernel<<<256, 256, 0, stream>>>(cand, count, x, centers, best);
  proj_mfma_kernel<<<dim3(Mc / 128, DOc / 128), 256, 0, stream>>>(ch, best, whT, b, out);
}

// Round 5
// 280.255 us; speedup vs baseline: 2.8123x; 2.3913x over previous
//
#include <hip/hip_runtime.h>
#include <float.h>
#include <stdint.h>

#define EPSF 1e-6f

constexpr int Dc = 512, Kc = 4096, DOc = 1024;
constexpr int Mc = 16384;                 // 4*4096 rows
constexpr int NHALF = 2048;               // centers per half-pass

typedef _Float16 f16x8 __attribute__((ext_vector_type(8)));
typedef float f32x4 __attribute__((ext_vector_type(4)));
typedef __attribute__((address_space(1))) unsigned int gu32;
typedef __attribute__((address_space(3))) unsigned int lu32;
typedef unsigned long long u64;

// ---------- convert x: f16 cast + per-row candidate window ----------
__global__ __launch_bounds__(256) void cvt_x_kernel(const float* __restrict__ x,
                                                    _Float16* __restrict__ xh,
                                                    unsigned* __restrict__ wthr) {
  const int lane = threadIdx.x & 63, w = threadIdx.x >> 6;
  const int row = blockIdx.x * 4 + w;
  const size_t base = (size_t)row * Dc + lane * 8;
  float4 v0 = *(const float4*)(x + base);
  float4 v1 = *(const float4*)(x + base + 4);
  float v[8] = {v0.x, v0.y, v0.z, v0.w, v1.x, v1.y, v1.z, v1.w};
  f16x8 h;
  float s = 0.f;
#pragma unroll
  for (int i = 0; i < 8; ++i) {
    const float q = v[i] + EPSF;
    h[i] = (_Float16)q;
    s += q * q;
  }
  *(f16x8*)(xh + base) = h;
#pragma unroll
  for (int m = 1; m < 64; m <<= 1) s += __shfl_xor(s, m, 64);
  // window (u16 quant units): 64*[2(2e+e^2)*||c||max*||x||] + slack; e=2^-11
  if (lane == 0) wthr[row] = (unsigned)(2.829f * sqrtf(s) + 8.0f);
}

__global__ __launch_bounds__(256) void cvt_c_kernel(const float* __restrict__ centers,
                                                    _Float16* __restrict__ ch,
                                                    float* __restrict__ c2) {
  const int lane = threadIdx.x & 63, w = threadIdx.x >> 6;
  const int row = blockIdx.x * 4 + w;
  const size_t base = (size_t)row * Dc + lane * 8;
  float4 v0 = *(const float4*)(centers + base);
  float4 v1 = *(const float4*)(centers + base + 4);
  float v[8] = {v0.x, v0.y, v0.z, v0.w, v1.x, v1.y, v1.z, v1.w};
  f16x8 h;
  float s = 0.f;
#pragma unroll
  for (int i = 0; i < 8; ++i) { s += v[i] * v[i]; h[i] = (_Float16)v[i]; }
  *(f16x8*)(ch + base) = h;
#pragma unroll
  for (int off = 32; off > 0; off >>= 1) s += __shfl_down(s, off, 64);
  if (lane == 0) c2[row] = s;
}

__global__ __launch_bounds__(256) void cvt_w_kernel(const float* __restrict__ W,
                                                    _Float16* __restrict__ whT) {
  const int g = blockIdx.x * 256 + threadIdx.x;
  const int n = g & (DOc - 1), d8 = g >> 10;
  f16x8 h;
#pragma unroll
  for (int r = 0; r < 8; ++r) h[r] = (_Float16)W[(size_t)(d8 * 8 + r) * DOc + n];
  *(f16x8*)(whT + (size_t)n * Dc + d8 * 8) = h;
}

// ---------- distance GEMM (hh only, m97 shape) + u16 quantized store ----------
__global__ __launch_bounds__(256, 2) void dist_hh_kernel(
    const _Float16* __restrict__ xh, const _Float16* __restrict__ chh,
    const float* __restrict__ c2h, unsigned short* __restrict__ dq) {
  constexpr int BM = 128, BN = 128, BK = 32;
  __shared__ __align__(16) _Float16 smem[2 * BM * BK];  // sA | sB; reused as u16 tile
  _Float16* sA = smem;
  _Float16* sB = smem + BM * BK;
  unsigned short* t = (unsigned short*)smem;            // [64][128] u16

  const int tid = threadIdx.x;
  const int lane = tid & 63, w = tid >> 6;
  const int n0 = blockIdx.x * BN;
  const int row0 = blockIdx.y * BM;
  const int srow = w * 16 + (lane >> 2);
  const int scol = (lane & 3) * 8;
  const int fr = lane & 15, kq = lane >> 4;
  const int m0 = w * 32;

  f32x4 acc[2][8];
#pragma unroll
  for (int i = 0; i < 2; ++i)
#pragma unroll
    for (int j = 0; j < 8; ++j) acc[i][j] = (f32x4){0.f, 0.f, 0.f, 0.f};

  for (int d0 = 0; d0 < Dc; d0 += BK) {
#pragma unroll
    for (int r = 0; r < 2; ++r) {
      const int rr = r * 64 + srow;
      const size_t gA = (size_t)(row0 + rr) * Dc + d0 + scol;
      const size_t gB = (size_t)(n0 + rr) * Dc + d0 + scol;
      const int lo = rr * BK + scol;
      __builtin_amdgcn_global_load_lds((const gu32*)(xh + gA), (lu32*)(sA + lo), 16, 0, 0);
      __builtin_amdgcn_global_load_lds((const gu32*)(chh + gB), (lu32*)(sB + lo), 16, 0, 0);
    }
    __syncthreads();

    f16x8 a[2], b[8];
#pragma unroll
    for (int i = 0; i < 2; ++i)
      a[i] = *(const f16x8*)&sA[(m0 + 16 * i + fr) * BK + kq * 8];
#pragma unroll
    for (int j = 0; j < 8; ++j)
      b[j] = *(const f16x8*)&sB[(16 * j + fr) * BK + kq * 8];
#pragma unroll
    for (int i = 0; i < 2; ++i)
#pragma unroll
      for (int j = 0; j < 8; ++j)
        acc[i][j] = __builtin_amdgcn_mfma_f32_16x16x32_f16(a[i], b[j], acc[i][j], 0, 0, 0);
    __syncthreads();
  }

  // epilogue: d~ = c2[n] - 2*dot, quantize u16 (step 1/32, offset 256),
  // LDS transpose to coalesced stores. Clamp-low is SAFE (clamped -> refined).
  float c2v[8];
#pragma unroll
  for (int j = 0; j < 8; ++j) c2v[j] = c2h[n0 + 16 * j + fr];

#pragma unroll
  for (int i = 0; i < 2; ++i) {
    __syncthreads();
#pragma unroll
    for (int reg = 0; reg < 4; ++reg) {
      const int lrow = w * 16 + kq * 4 + reg;
#pragma unroll
      for (int j = 0; j < 8; ++j) {
        const float d = c2v[j] - 2.0f * acc[i][j][reg];
        int u = __float2int_rn((d + 256.0f) * 32.0f);
        u = min(65535, max(0, u));
        t[lrow * 128 + 16 * j + fr] = (unsigned short)u;
      }
    }
    __syncthreads();
#pragma unroll
    for (int cc = 0; cc < 4; ++cc) {
      const int chk = tid + 256 * cc;
      const int lr = chk >> 4, c8 = chk & 15;
      const int grow = row0 + (lr >> 4) * 32 + 16 * i + (lr & 15);
      uint4 v = *(const uint4*)&t[lr * 128 + c8 * 8];
      *(uint4*)&dq[(size_t)grow * NHALF + n0 + c8 * 8] = v;
    }
  }
}

// ---------- fused scan+refine: one wave per (row, half), NO atomics ----------
__global__ __launch_bounds__(256) void scan_refine_kernel(
    const unsigned short* __restrict__ dq, const unsigned* __restrict__ wthr,
    const float* __restrict__ x, const float* __restrict__ centers,
    int halfbase, int mode, u64* __restrict__ best) {
  const int w = threadIdx.x >> 6, l = threadIdx.x & 63;
  const int row = blockIdx.x * 4 + w;
  const unsigned short* dr = dq + (size_t)row * NHALF;

  uint4 v[4];
#pragma unroll
  for (int k = 0; k < 4; ++k) v[k] = *(const uint4*)&dr[k * 512 + l * 8];

  // wave min of this row-half
  unsigned mn = 0xFFFFu;
#pragma unroll
  for (int k = 0; k < 4; ++k) {
    const unsigned* u = (const unsigned*)&v[k];
#pragma unroll
    for (int q = 0; q < 4; ++q) {
      mn = min(mn, u[q] & 0xFFFFu);
      mn = min(mn, u[q] >> 16);
    }
  }
#pragma unroll
  for (int m = 1; m < 64; m <<= 1) mn = min(mn, (unsigned)__shfl_xor((int)mn, m, 64));
  const unsigned thr = mn + wthr[row];

  // preload x row (fp32), 8 elems/lane
  const float* xr = x + (size_t)row * Dc + l * 8;
  float4 a0 = *(const float4*)xr, a1 = *(const float4*)(xr + 4);
  const float xa[8] = {a0.x, a0.y, a0.z, a0.w, a1.x, a1.y, a1.z, a1.w};
  double xq[8];
#pragma unroll
  for (int i = 0; i < 8; ++i) xq[i] = (double)(xa[i] + EPSF);  // fp32 x+eps, as reference

  u64 bk = ~0ULL;
  // ballot over the 32 per-lane slots; every hit gets a 64-lane fp64 dot
#pragma unroll
  for (int k = 0; k < 4; ++k) {
    const unsigned* u = (const unsigned*)&v[k];
#pragma unroll
    for (int t = 0; t < 8; ++t) {
      const unsigned uv = (u[t >> 1] >> ((t & 1) * 16)) & 0xFFFFu;
      u64 m = __ballot(uv <= thr);
      while (m) {
        const int ln = __ffsll((long long)m) - 1;
        m &= m - 1;
        const int g = halfbase + k * 512 + ln * 8 + t;
        const float* cr = centers + (size_t)g * Dc + l * 8;
        float4 b0 = *(const float4*)cr, b1 = *(const float4*)(cr + 4);
        const float ca[8] = {b0.x, b0.y, b0.z, b0.w, b1.x, b1.y, b1.z, b1.w};
        double s = 0.0;
#pragma unroll
        for (int i = 0; i < 8; ++i) {
          const double cd = (double)ca[i];
          s += cd * cd - 2.0 * xq[i] * cd;
        }
#pragma unroll
        for (int mm = 1; mm < 64; mm <<= 1) s += __shfl_xor(s, mm, 64);
        // sortable key: d2' shifted positive (|d2'| << 16384), low 12 bits = idx
        const u64 key =
            ((u64)__double_as_longlong(s + 16384.0) & ~0xFFFULL) | (unsigned)g;
        bk = min(bk, key);
      }
    }
  }
  if (l == 0) {
    if (mode) bk = min(bk, best[row]);
    best[row] = bk;
  }
}

// ---------- projection: out = centers[best] @ W + b  (f16 MFMA) ----------
__global__ __launch_bounds__(256, 2) void proj_mfma_kernel(
    const _Float16* __restrict__ ch, const u64* __restrict__ best,
    const _Float16* __restrict__ whT, const float* __restrict__ bias,
    float* __restrict__ out) {
  constexpr int BM = 128, BN = 128, BK = 32;
  __shared__ __align__(16) _Float16 sA[BM * BK], sB[BN * BK];
  __shared__ int ssel[BM];

  const int tid = threadIdx.x;
  const int lane = tid & 63, w = tid >> 6;
  const int row0 = blockIdx.x * BM;
  const int n0 = blockIdx.y * BN;
  const int srow = w * 16 + (lane >> 2);
  const int scol = (lane & 3) * 8;
  const int fr = lane & 15, kq = lane >> 4;
  const int m0 = w * 32;

  if (tid < BM) ssel[tid] = (int)(best[row0 + tid] & 0xFFFULL);
  __syncthreads();

  f32x4 acc[2][8];
#pragma unroll
  for (int i = 0; i < 2; ++i)
#pragma unroll
    for (int j = 0; j < 8; ++j) acc[i][j] = (f32x4){0.f, 0.f, 0.f, 0.f};

  for (int d0 = 0; d0 < Dc; d0 += BK) {
#pragma unroll
    for (int r = 0; r < 2; ++r) {
      const int rr = r * 64 + srow;
      const size_t gA = (size_t)ssel[rr] * Dc + d0 + scol;
      const size_t gB = (size_t)(n0 + rr) * Dc + d0 + scol;
      const int lo = rr * BK + scol;
      __builtin_amdgcn_global_load_lds((const gu32*)(ch + gA), (lu32*)(sA + lo), 16, 0, 0);
      __builtin_amdgcn_global_load_lds((const gu32*)(whT + gB), (lu32*)(sB + lo), 16, 0, 0);
    }
    __syncthreads();

    f16x8 a[2], b[8];
#pragma unroll
    for (int i = 0; i < 2; ++i)
      a[i] = *(const f16x8*)&sA[(m0 + 16 * i + fr) * BK + kq * 8];
#pragma unroll
    for (int j = 0; j < 8; ++j)
      b[j] = *(const f16x8*)&sB[(16 * j + fr) * BK + kq * 8];
#pragma unroll
    for (int i = 0; i < 2; ++i)
#pragma unroll
      for (int j = 0; j < 8; ++j)
        acc[i][j] = __builtin_amdgcn_mfma_f32_16x16x32_f16(a[i], b[j], acc[i][j], 0, 0, 0);
    __syncthreads();
  }

#pragma unroll
  for (int j = 0; j < 8; ++j) {
    const int col = n0 + 16 * j + fr;
    const float bb = bias[col];
#pragma unroll
    for (int i = 0; i < 2; ++i)
#pragma unroll
      for (int reg = 0; reg < 4; ++reg)
        out[(size_t)(row0 + m0 + 16 * i + 4 * kq + reg) * DOc + col] =
            acc[i][j][reg] + bb;
  }
}

extern "C" void kernel_launch(void* const* d_in, const int* in_sizes, int n_in,
                              void* d_out, int out_size, void* d_ws, size_t ws_size,
                              hipStream_t stream) {
  const float* x = (const float*)d_in[0];        // [4,4096,512]
  const float* centers = (const float*)d_in[1];  // [4096,512]
  const float* W = (const float*)d_in[2];        // [512,1024]
  const float* b = (const float*)d_in[3];        // [1024]
  float* out = (float*)d_out;                    // [4,4096,1024] fp32

  // dq (u16 [16384][2048] = 67.1 MB) lives in d_out; proj overwrites it last.
  unsigned short* dq = (unsigned short*)d_out;

  // workspace (~22.3 MB)
  char* ws = (char*)d_ws;
  _Float16* xh = (_Float16*)(ws);                 // 16.78 MB
  _Float16* ch = (_Float16*)(ws + 16777216);      // 4.19 MB
  _Float16* whT = (_Float16*)(ws + 20971520);     // 1.05 MB
  float* c2 = (float*)(ws + 22020096);            // 16 KB
  unsigned* wthr = (unsigned*)(ws + 22036480);    // 64 KB
  u64* best = (u64*)(ws + 22102016);              // 128 KB

  cvt_x_kernel<<<Mc / 4, 256, 0, stream>>>(x, xh, wthr);
  cvt_c_kernel<<<Kc / 4, 256, 0, stream>>>(centers, ch, c2);
  cvt_w_kernel<<<Dc * DOc / (256 * 8), 256, 0, stream>>>(W, whT);

  for (int half = 0; half < 2; ++half) {
    const int hb = half * NHALF;
    dist_hh_kernel<<<dim3(NHALF / 128, Mc / 128), 256, 0, stream>>>(
        xh, ch + (size_t)hb * Dc, c2 + hb, dq);
    scan_refine_kernel<<<Mc / 4, 256, 0, stream>>>(dq, wthr, x, centers, hb,
                                                   half, best);
  }
  proj_mfma_kernel<<<dim3(Mc / 128, DOc / 128), 256, 0, stream>>>(ch, best, whT, b, out);
}